// Round 1
// baseline (14418.109 us; speedup 1.0000x reference)
//
#include <hip/hip_runtime.h>

#define N_NODES 500000
#define N_EDGES 2000000
#define F_IN 117
#define H 128
#define NLAYERS 3

// ---------------- input projection: h = tanh(x @ W_in + b_in) ----------------
// W_in (117x128, zero-padded to 120 rows) in LDS; 8 rows/iter; each thread: 4 rows x 1 col.
__global__ __launch_bounds__(256) void proj_kernel(const float* __restrict__ x,
                                                   const float* __restrict__ Win,
                                                   const float* __restrict__ bin,
                                                   float* __restrict__ h) {
    __shared__ __align__(16) float Ws[120 * 128];
    __shared__ __align__(16) float xs[8 * 120];
    const int t = threadIdx.x;
    for (int i = t; i < 120 * 128; i += 256) {
        int k = i >> 7;
        Ws[i] = (k < F_IN) ? Win[i] : 0.f;   // Win is [117][128] row-major, same linear layout
    }
    const int c = t & 127;
    const int rh = t >> 7;               // 0..1 -> rows rh*4 .. rh*4+3 of the 8-row group
    const float bc = bin[c];

    const int ngroups = N_NODES / 8;     // 62500
    for (int g = blockIdx.x; g < ngroups; g += gridDim.x) {
        const int r0 = g * 8;
        __syncthreads();                 // previous iter done reading xs (also covers Ws load)
        {   // stage 8 rows of x (936 contiguous floats), pad each LDS row to 120
            const float* gx = x + (size_t)r0 * F_IN;
            for (int i = t; i < 8 * F_IN; i += 256) {
                int rr = i / F_IN;
                int kk = i - rr * F_IN;
                xs[rr * 120 + kk] = gx[i];
            }
            if (t < 24) { int rr = t / 3; xs[rr * 120 + F_IN + (t % 3)] = 0.f; }
        }
        __syncthreads();
        float acc0 = 0.f, acc1 = 0.f, acc2 = 0.f, acc3 = 0.f;
        const float* xr = xs + (rh * 4) * 120;
        #pragma unroll 6
        for (int k = 0; k < 120; k += 4) {
            const float w0 = Ws[(k + 0) * 128 + c];
            const float w1 = Ws[(k + 1) * 128 + c];
            const float w2 = Ws[(k + 2) * 128 + c];
            const float w3 = Ws[(k + 3) * 128 + c];
            const float4 x0 = *(const float4*)(xr + 0 * 120 + k);
            const float4 x1 = *(const float4*)(xr + 1 * 120 + k);
            const float4 x2 = *(const float4*)(xr + 2 * 120 + k);
            const float4 x3 = *(const float4*)(xr + 3 * 120 + k);
            acc0 = fmaf(x0.w, w3, fmaf(x0.z, w2, fmaf(x0.y, w1, fmaf(x0.x, w0, acc0))));
            acc1 = fmaf(x1.w, w3, fmaf(x1.z, w2, fmaf(x1.y, w1, fmaf(x1.x, w0, acc1))));
            acc2 = fmaf(x2.w, w3, fmaf(x2.z, w2, fmaf(x2.y, w1, fmaf(x2.x, w0, acc2))));
            acc3 = fmaf(x3.w, w3, fmaf(x3.z, w2, fmaf(x3.y, w1, fmaf(x3.x, w0, acc3))));
        }
        float* hw = h + (size_t)(r0 + rh * 4) * H + c;
        hw[0 * H] = tanhf(acc0 + bc);
        hw[1 * H] = tanhf(acc1 + bc);
        hw[2 * H] = tanhf(acc2 + bc);
        hw[3 * H] = tanhf(acc3 + bc);
    }
}

// ---------------- helpers ----------------
__global__ void zero4_kernel(float4* __restrict__ p, int n4) {
    const float4 z = {0.f, 0.f, 0.f, 0.f};
    for (int i = blockIdx.x * blockDim.x + threadIdx.x; i < n4; i += gridDim.x * blockDim.x)
        p[i] = z;
}

__global__ void zero1_kernel(float* __restrict__ p, int n) {
    int i = blockIdx.x * blockDim.x + threadIdx.x;
    if (i < n) p[i] = 0.f;
}

__global__ void deg_kernel(const int* __restrict__ dst, float* __restrict__ deg) {
    int e = blockIdx.x * blockDim.x + threadIdx.x;
    if (e < N_EDGES) unsafeAtomicAdd(&deg[dst[e]], 1.0f);
}

__global__ void inv_kernel(float* __restrict__ deg) {
    int n = blockIdx.x * blockDim.x + threadIdx.x;
    if (n < N_NODES) deg[n] = 1.0f / fmaxf(deg[n], 1.0f);
}

// ---------------- scatter: ns[dst] += h[src]  (32 threads/edge, float4 + 4 atomics) ----
__global__ __launch_bounds__(256) void scatter_kernel(const int* __restrict__ src,
                                                      const int* __restrict__ dst,
                                                      const float* __restrict__ h,
                                                      float* __restrict__ ns) {
    int idx = blockIdx.x * 256 + threadIdx.x;
    int e = idx >> 5;
    if (e >= N_EDGES) return;
    int f = (idx & 31) * 4;
    int s = src[e], d = dst[e];
    const float4 v = *(const float4*)(h + (size_t)s * H + f);
    float* p = ns + (size_t)d * H + f;
    unsafeAtomicAdd(p + 0, v.x);
    unsafeAtomicAdd(p + 1, v.y);
    unsafeAtomicAdd(p + 2, v.z);
    unsafeAtomicAdd(p + 3, v.w);
}

// ---------------- combine: h = relu(h @ Wself + (ns*inv) @ Wneigh + b)  (in place) ----
// Both 128x128 W matrices in dynamic LDS (128KB) + 16-row h/ns stage (16KB).
__global__ __launch_bounds__(512) void combine_kernel(const float* __restrict__ Wself,
                                                      const float* __restrict__ Wneigh,
                                                      const float* __restrict__ bl,
                                                      const float* __restrict__ ns,
                                                      const float* __restrict__ invdeg,
                                                      float* __restrict__ h) {
    extern __shared__ float lds[];
    float* Ws  = lds;               // 16384
    float* Wn  = lds + 16384;       // 16384
    float* hs  = lds + 32768;       // 2048
    float* nss = lds + 32768 + 2048;// 2048
    const int t = threadIdx.x;
    for (int i = t; i < 16384; i += 512) { Ws[i] = Wself[i]; Wn[i] = Wneigh[i]; }
    const int c = t & 127;
    const int rh = t >> 7;          // 0..3 -> rows rh*4 .. rh*4+3 of the 16-row group
    const float bc = bl[c];

    const int ngroups = N_NODES / 16;   // 31250
    for (int g = blockIdx.x; g < ngroups; g += gridDim.x) {
        const int r0 = g * 16;
        __syncthreads();            // prev iter done reading hs/nss (covers W load on iter 1)
        {   // stage 16 rows: each thread one float4 of h and of ns (scaled by invdeg)
            const float4 hv = *((const float4*)(h  + (size_t)r0 * H) + t);
            float4       nv = *((const float4*)(ns + (size_t)r0 * H) + t);
            const float inv = invdeg[r0 + (t >> 5)];
            nv.x *= inv; nv.y *= inv; nv.z *= inv; nv.w *= inv;
            ((float4*)hs)[t]  = hv;
            ((float4*)nss)[t] = nv;
        }
        __syncthreads();
        float acc0 = bc, acc1 = bc, acc2 = bc, acc3 = bc;
        {
            const float* xr = hs + (rh * 4) * 128;
            #pragma unroll 4
            for (int k = 0; k < 128; k += 4) {
                const float w0 = Ws[(k + 0) * 128 + c];
                const float w1 = Ws[(k + 1) * 128 + c];
                const float w2 = Ws[(k + 2) * 128 + c];
                const float w3 = Ws[(k + 3) * 128 + c];
                const float4 x0 = *(const float4*)(xr + 0 * 128 + k);
                const float4 x1 = *(const float4*)(xr + 1 * 128 + k);
                const float4 x2 = *(const float4*)(xr + 2 * 128 + k);
                const float4 x3 = *(const float4*)(xr + 3 * 128 + k);
                acc0 = fmaf(x0.w, w3, fmaf(x0.z, w2, fmaf(x0.y, w1, fmaf(x0.x, w0, acc0))));
                acc1 = fmaf(x1.w, w3, fmaf(x1.z, w2, fmaf(x1.y, w1, fmaf(x1.x, w0, acc1))));
                acc2 = fmaf(x2.w, w3, fmaf(x2.z, w2, fmaf(x2.y, w1, fmaf(x2.x, w0, acc2))));
                acc3 = fmaf(x3.w, w3, fmaf(x3.z, w2, fmaf(x3.y, w1, fmaf(x3.x, w0, acc3))));
            }
        }
        {
            const float* xr = nss + (rh * 4) * 128;
            #pragma unroll 4
            for (int k = 0; k < 128; k += 4) {
                const float w0 = Wn[(k + 0) * 128 + c];
                const float w1 = Wn[(k + 1) * 128 + c];
                const float w2 = Wn[(k + 2) * 128 + c];
                const float w3 = Wn[(k + 3) * 128 + c];
                const float4 x0 = *(const float4*)(xr + 0 * 128 + k);
                const float4 x1 = *(const float4*)(xr + 1 * 128 + k);
                const float4 x2 = *(const float4*)(xr + 2 * 128 + k);
                const float4 x3 = *(const float4*)(xr + 3 * 128 + k);
                acc0 = fmaf(x0.w, w3, fmaf(x0.z, w2, fmaf(x0.y, w1, fmaf(x0.x, w0, acc0))));
                acc1 = fmaf(x1.w, w3, fmaf(x1.z, w2, fmaf(x1.y, w1, fmaf(x1.x, w0, acc1))));
                acc2 = fmaf(x2.w, w3, fmaf(x2.z, w2, fmaf(x2.y, w1, fmaf(x2.x, w0, acc2))));
                acc3 = fmaf(x3.w, w3, fmaf(x3.z, w2, fmaf(x3.y, w1, fmaf(x3.x, w0, acc3))));
            }
        }
        float* hw = h + (size_t)(r0 + rh * 4) * H + c;
        hw[0 * H] = fmaxf(acc0, 0.f);
        hw[1 * H] = fmaxf(acc1, 0.f);
        hw[2 * H] = fmaxf(acc2, 0.f);
        hw[3 * H] = fmaxf(acc3, 0.f);
    }
}

// ---------------- launch ----------------
extern "C" void kernel_launch(void* const* d_in, const int* in_sizes, int n_in,
                              void* d_out, int out_size, void* d_ws, size_t ws_size,
                              hipStream_t stream) {
    const float* x        = (const float*)d_in[0];
    const int*   edge_src = (const int*)d_in[1];
    const int*   edge_dst = (const int*)d_in[2];
    const float* W_in     = (const float*)d_in[3];
    const float* b_in     = (const float*)d_in[4];
    const float* W_self   = (const float*)d_in[5];
    const float* W_neigh  = (const float*)d_in[6];
    const float* b_layers = (const float*)d_in[7];

    float* h   = (float*)d_out;                       // 500000*128 floats, used in place
    float* ns  = (float*)d_ws;                        // 64,000,000 floats
    float* deg = ns + (size_t)N_NODES * H;            // 500,000 floats (becomes inv_deg)

    // input projection
    proj_kernel<<<512, 256, 0, stream>>>(x, W_in, b_in, h);

    // degrees -> inverse degrees
    zero1_kernel<<<(N_NODES + 255) / 256, 256, 0, stream>>>(deg, N_NODES);
    deg_kernel<<<(N_EDGES + 255) / 256, 256, 0, stream>>>(edge_dst, deg);
    inv_kernel<<<(N_NODES + 255) / 256, 256, 0, stream>>>(deg);

    const size_t lds_bytes = (16384 * 2 + 2048 * 2) * sizeof(float);  // 147456
    for (int l = 0; l < NLAYERS; ++l) {
        zero4_kernel<<<4096, 256, 0, stream>>>((float4*)ns, N_NODES * H / 4);
        scatter_kernel<<<N_EDGES * 32 / 256, 256, 0, stream>>>(edge_src, edge_dst, h, ns);
        combine_kernel<<<256, 512, lds_bytes, stream>>>(W_self + (size_t)l * H * H,
                                                        W_neigh + (size_t)l * H * H,
                                                        b_layers + (size_t)l * H,
                                                        ns, deg, h);
    }
}

// Round 2
// 4890.794 us; speedup vs baseline: 2.9480x; 2.9480x over previous
//
#include <hip/hip_runtime.h>

#define N_NODES 500000
#define N_EDGES 2000000
#define F_IN 117
#define H 128
#define NLAYERS 3

#define SCAN_E 2048
#define NB_SCAN ((N_NODES + SCAN_E - 1) / SCAN_E)   // 245

// ---------------- input projection: h = tanh(x @ W_in + b_in) ----------------
__global__ __launch_bounds__(256) void proj_kernel(const float* __restrict__ x,
                                                   const float* __restrict__ Win,
                                                   const float* __restrict__ bin,
                                                   float* __restrict__ h) {
    __shared__ __align__(16) float Ws[120 * 128];
    __shared__ __align__(16) float xs[8 * 120];
    const int t = threadIdx.x;
    for (int i = t; i < 120 * 128; i += 256) {
        int k = i >> 7;
        Ws[i] = (k < F_IN) ? Win[i] : 0.f;
    }
    const int c = t & 127;
    const int rh = t >> 7;
    const float bc = bin[c];

    const int ngroups = N_NODES / 8;     // 62500
    for (int g = blockIdx.x; g < ngroups; g += gridDim.x) {
        const int r0 = g * 8;
        __syncthreads();
        {
            const float* gx = x + (size_t)r0 * F_IN;
            for (int i = t; i < 8 * F_IN; i += 256) {
                int rr = i / F_IN;
                int kk = i - rr * F_IN;
                xs[rr * 120 + kk] = gx[i];
            }
            if (t < 24) { int rr = t / 3; xs[rr * 120 + F_IN + (t % 3)] = 0.f; }
        }
        __syncthreads();
        float acc0 = 0.f, acc1 = 0.f, acc2 = 0.f, acc3 = 0.f;
        const float* xr = xs + (rh * 4) * 120;
        #pragma unroll 6
        for (int k = 0; k < 120; k += 4) {
            const float w0 = Ws[(k + 0) * 128 + c];
            const float w1 = Ws[(k + 1) * 128 + c];
            const float w2 = Ws[(k + 2) * 128 + c];
            const float w3 = Ws[(k + 3) * 128 + c];
            const float4 x0 = *(const float4*)(xr + 0 * 120 + k);
            const float4 x1 = *(const float4*)(xr + 1 * 120 + k);
            const float4 x2 = *(const float4*)(xr + 2 * 120 + k);
            const float4 x3 = *(const float4*)(xr + 3 * 120 + k);
            acc0 = fmaf(x0.w, w3, fmaf(x0.z, w2, fmaf(x0.y, w1, fmaf(x0.x, w0, acc0))));
            acc1 = fmaf(x1.w, w3, fmaf(x1.z, w2, fmaf(x1.y, w1, fmaf(x1.x, w0, acc1))));
            acc2 = fmaf(x2.w, w3, fmaf(x2.z, w2, fmaf(x2.y, w1, fmaf(x2.x, w0, acc2))));
            acc3 = fmaf(x3.w, w3, fmaf(x3.z, w2, fmaf(x3.y, w1, fmaf(x3.x, w0, acc3))));
        }
        float* hw = h + (size_t)(r0 + rh * 4) * H + c;
        hw[0 * H] = tanhf(acc0 + bc);
        hw[1 * H] = tanhf(acc1 + bc);
        hw[2 * H] = tanhf(acc2 + bc);
        hw[3 * H] = tanhf(acc3 + bc);
    }
}

// ---------------- CSR build ----------------
__global__ void zero_int_kernel(int* __restrict__ p, int n) {
    int i = blockIdx.x * blockDim.x + threadIdx.x;
    if (i < n) p[i] = 0;
}

__global__ void hist_kernel(const int* __restrict__ dst, int* __restrict__ cnt) {
    int e = blockIdx.x * blockDim.x + threadIdx.x;
    if (e < N_EDGES) atomicAdd(&cnt[dst[e]], 1);
}

__global__ __launch_bounds__(256) void scan_reduce_kernel(const int* __restrict__ cnt,
                                                          int* __restrict__ bsums) {
    __shared__ int s[256];
    const int base = blockIdx.x * SCAN_E;
    int sum = 0;
    for (int i = threadIdx.x; i < SCAN_E; i += 256) {
        int idx = base + i;
        sum += (idx < N_NODES) ? cnt[idx] : 0;
    }
    s[threadIdx.x] = sum;
    __syncthreads();
    for (int off = 128; off > 0; off >>= 1) {
        if (threadIdx.x < off) s[threadIdx.x] += s[threadIdx.x + off];
        __syncthreads();
    }
    if (threadIdx.x == 0) bsums[blockIdx.x] = s[0];
}

__global__ void scan_bsums_kernel(int* __restrict__ bsums) {   // 1 block, 256 threads
    __shared__ int s[256];
    const int tid = threadIdx.x;
    int v = (tid < NB_SCAN) ? bsums[tid] : 0;
    s[tid] = v;
    __syncthreads();
    for (int off = 1; off < 256; off <<= 1) {
        int add = (tid >= off) ? s[tid - off] : 0;
        __syncthreads();
        s[tid] += add;
        __syncthreads();
    }
    if (tid < NB_SCAN) bsums[tid] = s[tid] - v;   // exclusive
}

__global__ __launch_bounds__(256) void scan_final_kernel(const int* __restrict__ cnt,
                                                         const int* __restrict__ bsums,
                                                         int* __restrict__ start,
                                                         int* __restrict__ cursor,
                                                         float* __restrict__ inv) {
    __shared__ int tsum[256];
    const int tid = threadIdx.x;
    const int base = blockIdx.x * SCAN_E + tid * 8;
    int c[8];
    int s = 0;
    #pragma unroll
    for (int k = 0; k < 8; ++k) {
        int idx = base + k;
        c[k] = (idx < N_NODES) ? cnt[idx] : 0;
        s += c[k];
    }
    tsum[tid] = s;
    __syncthreads();
    for (int off = 1; off < 256; off <<= 1) {
        int add = (tid >= off) ? tsum[tid - off] : 0;
        __syncthreads();
        tsum[tid] += add;
        __syncthreads();
    }
    int off0 = bsums[blockIdx.x] + tsum[tid] - s;  // exclusive prefix for this thread
    #pragma unroll
    for (int k = 0; k < 8; ++k) {
        int idx = base + k;
        if (idx < N_NODES) {
            start[idx]  = off0;
            cursor[idx] = off0;
            inv[idx]    = 1.0f / fmaxf((float)c[k], 1.0f);
            off0 += c[k];
        }
    }
}

__global__ void fill_kernel(const int* __restrict__ src, const int* __restrict__ dst,
                            int* __restrict__ cursor, int* __restrict__ srcs) {
    int e = blockIdx.x * blockDim.x + threadIdx.x;
    if (e < N_EDGES) {
        int pos = atomicAdd(&cursor[dst[e]], 1);
        srcs[pos] = src[e];
    }
}

// ---------------- gather: ns[n] = mean_{s in nbr(n)} h[s]  (32 lanes/node, float4) ----
__global__ __launch_bounds__(256) void gather_kernel(const int* __restrict__ start,
                                                     const int* __restrict__ cnt,
                                                     const int* __restrict__ srcs,
                                                     const float* __restrict__ inv,
                                                     const float* __restrict__ h,
                                                     float* __restrict__ ns) {
    const int idx  = blockIdx.x * 256 + threadIdx.x;
    const int node = idx >> 5;
    if (node >= N_NODES) return;
    const int f = (idx & 31) * 4;
    const int st = start[node];
    const int c  = cnt[node];
    float4 acc = {0.f, 0.f, 0.f, 0.f};
    int j = 0;
    for (; j + 1 < c; j += 2) {
        const int s0 = srcs[st + j];
        const int s1 = srcs[st + j + 1];
        const float4 v0 = *(const float4*)(h + (size_t)s0 * H + f);
        const float4 v1 = *(const float4*)(h + (size_t)s1 * H + f);
        acc.x += v0.x; acc.y += v0.y; acc.z += v0.z; acc.w += v0.w;
        acc.x += v1.x; acc.y += v1.y; acc.z += v1.z; acc.w += v1.w;
    }
    if (j < c) {
        const int s0 = srcs[st + j];
        const float4 v0 = *(const float4*)(h + (size_t)s0 * H + f);
        acc.x += v0.x; acc.y += v0.y; acc.z += v0.z; acc.w += v0.w;
    }
    const float iv = inv[node];
    float4 o = {acc.x * iv, acc.y * iv, acc.z * iv, acc.w * iv};
    *(float4*)(ns + (size_t)node * H + f) = o;
}

// ---------------- combine: h = relu(h @ Wself + ns @ Wneigh + b)  (ns already mean) ----
__global__ __launch_bounds__(512) void combine_kernel(const float* __restrict__ Wself,
                                                      const float* __restrict__ Wneigh,
                                                      const float* __restrict__ bl,
                                                      const float* __restrict__ ns,
                                                      float* __restrict__ h) {
    extern __shared__ float lds[];
    float* Ws  = lds;                // 16384
    float* Wn  = lds + 16384;        // 16384
    float* hs  = lds + 32768;        // 2048
    float* nss = lds + 32768 + 2048; // 2048
    const int t = threadIdx.x;
    for (int i = t; i < 16384; i += 512) { Ws[i] = Wself[i]; Wn[i] = Wneigh[i]; }
    const int c = t & 127;
    const int rh = t >> 7;
    const float bc = bl[c];

    const int ngroups = N_NODES / 16;   // 31250
    for (int g = blockIdx.x; g < ngroups; g += gridDim.x) {
        const int r0 = g * 16;
        __syncthreads();
        {
            const float4 hv = *((const float4*)(h  + (size_t)r0 * H) + t);
            const float4 nv = *((const float4*)(ns + (size_t)r0 * H) + t);
            ((float4*)hs)[t]  = hv;
            ((float4*)nss)[t] = nv;
        }
        __syncthreads();
        float acc0 = bc, acc1 = bc, acc2 = bc, acc3 = bc;
        {
            const float* xr = hs + (rh * 4) * 128;
            #pragma unroll 4
            for (int k = 0; k < 128; k += 4) {
                const float w0 = Ws[(k + 0) * 128 + c];
                const float w1 = Ws[(k + 1) * 128 + c];
                const float w2 = Ws[(k + 2) * 128 + c];
                const float w3 = Ws[(k + 3) * 128 + c];
                const float4 x0 = *(const float4*)(xr + 0 * 128 + k);
                const float4 x1 = *(const float4*)(xr + 1 * 128 + k);
                const float4 x2 = *(const float4*)(xr + 2 * 128 + k);
                const float4 x3 = *(const float4*)(xr + 3 * 128 + k);
                acc0 = fmaf(x0.w, w3, fmaf(x0.z, w2, fmaf(x0.y, w1, fmaf(x0.x, w0, acc0))));
                acc1 = fmaf(x1.w, w3, fmaf(x1.z, w2, fmaf(x1.y, w1, fmaf(x1.x, w0, acc1))));
                acc2 = fmaf(x2.w, w3, fmaf(x2.z, w2, fmaf(x2.y, w1, fmaf(x2.x, w0, acc2))));
                acc3 = fmaf(x3.w, w3, fmaf(x3.z, w2, fmaf(x3.y, w1, fmaf(x3.x, w0, acc3))));
            }
        }
        {
            const float* xr = nss + (rh * 4) * 128;
            #pragma unroll 4
            for (int k = 0; k < 128; k += 4) {
                const float w0 = Wn[(k + 0) * 128 + c];
                const float w1 = Wn[(k + 1) * 128 + c];
                const float w2 = Wn[(k + 2) * 128 + c];
                const float w3 = Wn[(k + 3) * 128 + c];
                const float4 x0 = *(const float4*)(xr + 0 * 128 + k);
                const float4 x1 = *(const float4*)(xr + 1 * 128 + k);
                const float4 x2 = *(const float4*)(xr + 2 * 128 + k);
                const float4 x3 = *(const float4*)(xr + 3 * 128 + k);
                acc0 = fmaf(x0.w, w3, fmaf(x0.z, w2, fmaf(x0.y, w1, fmaf(x0.x, w0, acc0))));
                acc1 = fmaf(x1.w, w3, fmaf(x1.z, w2, fmaf(x1.y, w1, fmaf(x1.x, w0, acc1))));
                acc2 = fmaf(x2.w, w3, fmaf(x2.z, w2, fmaf(x2.y, w1, fmaf(x2.x, w0, acc2))));
                acc3 = fmaf(x3.w, w3, fmaf(x3.z, w2, fmaf(x3.y, w1, fmaf(x3.x, w0, acc3))));
            }
        }
        float* hw = h + (size_t)(r0 + rh * 4) * H + c;
        hw[0 * H] = fmaxf(acc0, 0.f);
        hw[1 * H] = fmaxf(acc1, 0.f);
        hw[2 * H] = fmaxf(acc2, 0.f);
        hw[3 * H] = fmaxf(acc3, 0.f);
    }
}

// ---------------- launch ----------------
extern "C" void kernel_launch(void* const* d_in, const int* in_sizes, int n_in,
                              void* d_out, int out_size, void* d_ws, size_t ws_size,
                              hipStream_t stream) {
    const float* x        = (const float*)d_in[0];
    const int*   edge_src = (const int*)d_in[1];
    const int*   edge_dst = (const int*)d_in[2];
    const float* W_in     = (const float*)d_in[3];
    const float* b_in     = (const float*)d_in[4];
    const float* W_self   = (const float*)d_in[5];
    const float* W_neigh  = (const float*)d_in[6];
    const float* b_layers = (const float*)d_in[7];

    float* h  = (float*)d_out;                         // in-place feature buffer
    float* ns = (float*)d_ws;                          // 64,000,000 floats (256 MB)
    int*   cnt    = (int*)(ns + (size_t)N_NODES * H);  // 500,000
    int*   start  = cnt + N_NODES;                     // 500,000
    int*   cursor = start + N_NODES;                   // 500,000
    float* inv    = (float*)(cursor + N_NODES);        // 500,000
    int*   srcs   = (int*)(inv + N_NODES);             // 2,000,000
    int*   bsums  = srcs + N_EDGES;                    // NB_SCAN (<=256)

    // input projection
    proj_kernel<<<512, 256, 0, stream>>>(x, W_in, b_in, h);

    // CSR build (once; edge_dst is static)
    zero_int_kernel<<<(N_NODES + 255) / 256, 256, 0, stream>>>(cnt, N_NODES);
    hist_kernel<<<(N_EDGES + 255) / 256, 256, 0, stream>>>(edge_dst, cnt);
    scan_reduce_kernel<<<NB_SCAN, 256, 0, stream>>>(cnt, bsums);
    scan_bsums_kernel<<<1, 256, 0, stream>>>(bsums);
    scan_final_kernel<<<NB_SCAN, 256, 0, stream>>>(cnt, bsums, start, cursor, inv);
    fill_kernel<<<(N_EDGES + 255) / 256, 256, 0, stream>>>(edge_src, edge_dst, cursor, srcs);

    const size_t lds_bytes = (16384 * 2 + 2048 * 2) * sizeof(float);  // 147456
    for (int l = 0; l < NLAYERS; ++l) {
        gather_kernel<<<(N_NODES * 32 + 255) / 256, 256, 0, stream>>>(start, cnt, srcs, inv, h, ns);
        combine_kernel<<<256, 512, lds_bytes, stream>>>(W_self + (size_t)l * H * H,
                                                        W_neigh + (size_t)l * H * H,
                                                        b_layers + (size_t)l * H,
                                                        ns, h);
    }
}

// Round 3
// 1756.897 us; speedup vs baseline: 8.2066x; 2.7838x over previous
//
#include <hip/hip_runtime.h>

#define N_NODES 500000
#define N_EDGES 2000000
#define F_IN 117
#define H 128
#define NLAYERS 3

#define SCAN_E 2048
#define NB_SCAN ((N_NODES + SCAN_E - 1) / SCAN_E)   // 245

typedef __attribute__((ext_vector_type(8))) short short8v;   // 8 bf16 (4 VGPR)
typedef __attribute__((ext_vector_type(4))) float f32x4;

__device__ __forceinline__ unsigned short f2bf(float x) {    // RNE fp32->bf16
    unsigned u = __builtin_bit_cast(unsigned, x);
    u += 0x7FFFu + ((u >> 16) & 1u);
    return (unsigned short)(u >> 16);
}
__device__ __forceinline__ float bf2f(unsigned short s) {
    unsigned u = ((unsigned)s) << 16;
    return __builtin_bit_cast(float, u);
}

// ---------------- input projection: h_bf = bf16(tanh(x @ W_in + b_in)) ----------------
__global__ __launch_bounds__(256) void proj_kernel(const float* __restrict__ x,
                                                   const float* __restrict__ Win,
                                                   const float* __restrict__ bin,
                                                   unsigned short* __restrict__ hb) {
    __shared__ __align__(16) float Ws[120 * 128];
    __shared__ __align__(16) float xs[8 * 120];
    const int t = threadIdx.x;
    for (int i = t; i < 120 * 128; i += 256) {
        int k = i >> 7;
        Ws[i] = (k < F_IN) ? Win[i] : 0.f;
    }
    const int c = t & 127;
    const int rh = t >> 7;
    const float bc = bin[c];

    const int ngroups = N_NODES / 8;     // 62500
    for (int g = blockIdx.x; g < ngroups; g += gridDim.x) {
        const int r0 = g * 8;
        __syncthreads();
        {
            const float* gx = x + (size_t)r0 * F_IN;
            for (int i = t; i < 8 * F_IN; i += 256) {
                int rr = i / F_IN;
                int kk = i - rr * F_IN;
                xs[rr * 120 + kk] = gx[i];
            }
            if (t < 24) { int rr = t / 3; xs[rr * 120 + F_IN + (t % 3)] = 0.f; }
        }
        __syncthreads();
        float acc0 = 0.f, acc1 = 0.f, acc2 = 0.f, acc3 = 0.f;
        const float* xr = xs + (rh * 4) * 120;
        #pragma unroll 6
        for (int k = 0; k < 120; k += 4) {
            const float w0 = Ws[(k + 0) * 128 + c];
            const float w1 = Ws[(k + 1) * 128 + c];
            const float w2 = Ws[(k + 2) * 128 + c];
            const float w3 = Ws[(k + 3) * 128 + c];
            const float4 x0 = *(const float4*)(xr + 0 * 120 + k);
            const float4 x1 = *(const float4*)(xr + 1 * 120 + k);
            const float4 x2 = *(const float4*)(xr + 2 * 120 + k);
            const float4 x3 = *(const float4*)(xr + 3 * 120 + k);
            acc0 = fmaf(x0.w, w3, fmaf(x0.z, w2, fmaf(x0.y, w1, fmaf(x0.x, w0, acc0))));
            acc1 = fmaf(x1.w, w3, fmaf(x1.z, w2, fmaf(x1.y, w1, fmaf(x1.x, w0, acc1))));
            acc2 = fmaf(x2.w, w3, fmaf(x2.z, w2, fmaf(x2.y, w1, fmaf(x2.x, w0, acc2))));
            acc3 = fmaf(x3.w, w3, fmaf(x3.z, w2, fmaf(x3.y, w1, fmaf(x3.x, w0, acc3))));
        }
        unsigned short* hw = hb + (size_t)(r0 + rh * 4) * H + c;
        hw[0 * H] = f2bf(tanhf(acc0 + bc));
        hw[1 * H] = f2bf(tanhf(acc1 + bc));
        hw[2 * H] = f2bf(tanhf(acc2 + bc));
        hw[3 * H] = f2bf(tanhf(acc3 + bc));
    }
}

// ---------------- CSR build ----------------
__global__ void zero_int_kernel(int* __restrict__ p, int n) {
    int i = blockIdx.x * blockDim.x + threadIdx.x;
    if (i < n) p[i] = 0;
}

__global__ void hist_kernel(const int* __restrict__ dst, int* __restrict__ cnt) {
    int e = blockIdx.x * blockDim.x + threadIdx.x;
    if (e < N_EDGES) atomicAdd(&cnt[dst[e]], 1);
}

__global__ __launch_bounds__(256) void scan_reduce_kernel(const int* __restrict__ cnt,
                                                          int* __restrict__ bsums) {
    __shared__ int s[256];
    const int base = blockIdx.x * SCAN_E;
    int sum = 0;
    for (int i = threadIdx.x; i < SCAN_E; i += 256) {
        int idx = base + i;
        sum += (idx < N_NODES) ? cnt[idx] : 0;
    }
    s[threadIdx.x] = sum;
    __syncthreads();
    for (int off = 128; off > 0; off >>= 1) {
        if (threadIdx.x < off) s[threadIdx.x] += s[threadIdx.x + off];
        __syncthreads();
    }
    if (threadIdx.x == 0) bsums[blockIdx.x] = s[0];
}

__global__ void scan_bsums_kernel(int* __restrict__ bsums) {   // 1 block, 256 threads
    __shared__ int s[256];
    const int tid = threadIdx.x;
    int v = (tid < NB_SCAN) ? bsums[tid] : 0;
    s[tid] = v;
    __syncthreads();
    for (int off = 1; off < 256; off <<= 1) {
        int add = (tid >= off) ? s[tid - off] : 0;
        __syncthreads();
        s[tid] += add;
        __syncthreads();
    }
    if (tid < NB_SCAN) bsums[tid] = s[tid] - v;   // exclusive
}

__global__ __launch_bounds__(256) void scan_final_kernel(const int* __restrict__ cnt,
                                                         const int* __restrict__ bsums,
                                                         int* __restrict__ start,
                                                         int* __restrict__ cursor,
                                                         float* __restrict__ inv) {
    __shared__ int tsum[256];
    const int tid = threadIdx.x;
    const int base = blockIdx.x * SCAN_E + tid * 8;
    int c[8];
    int s = 0;
    #pragma unroll
    for (int k = 0; k < 8; ++k) {
        int idx = base + k;
        c[k] = (idx < N_NODES) ? cnt[idx] : 0;
        s += c[k];
    }
    tsum[tid] = s;
    __syncthreads();
    for (int off = 1; off < 256; off <<= 1) {
        int add = (tid >= off) ? tsum[tid - off] : 0;
        __syncthreads();
        tsum[tid] += add;
        __syncthreads();
    }
    int off0 = bsums[blockIdx.x] + tsum[tid] - s;
    #pragma unroll
    for (int k = 0; k < 8; ++k) {
        int idx = base + k;
        if (idx < N_NODES) {
            start[idx]  = off0;
            cursor[idx] = off0;
            inv[idx]    = 1.0f / fmaxf((float)c[k], 1.0f);
            off0 += c[k];
        }
    }
}

__global__ void fill_kernel(const int* __restrict__ src, const int* __restrict__ dst,
                            int* __restrict__ cursor, int* __restrict__ srcs) {
    int e = blockIdx.x * blockDim.x + threadIdx.x;
    if (e < N_EDGES) {
        int pos = atomicAdd(&cursor[dst[e]], 1);
        srcs[pos] = src[e];
    }
}

// ---------------- W prep: fp32 [Wself;Wneigh] -> bf16 MFMA B-fragment order -----------
// Wfrag[l][fi][lane][j], fi = (wc*4+ct)*8+ks ; lane gets B[k=ks*32+(lane>>4)*8+j][c],
// c = wc*64+ct*16+(lane&15).
__global__ void prep_w_kernel(const float* __restrict__ Wself,
                              const float* __restrict__ Wneigh,
                              short* __restrict__ Wfrag) {
    const int tid = blockIdx.x * 256 + threadIdx.x;     // < 3*64*64
    if (tid >= NLAYERS * 64 * 64) return;
    const int lane = tid & 63;
    const int fi   = (tid >> 6) & 63;
    const int l    = tid >> 12;
    const int ks = fi & 7, ct = (fi >> 3) & 3, wc = fi >> 5;
    const int c = wc * 64 + ct * 16 + (lane & 15);
    const int kbase = ks * 32 + (lane >> 4) * 8;
    short8v out;
    #pragma unroll
    for (int j = 0; j < 8; ++j) {
        int k = kbase + j;
        float v = (k < 128) ? Wself [(size_t)l * H * H + k * H + c]
                            : Wneigh[(size_t)l * H * H + (k - 128) * H + c];
        out[j] = (short)f2bf(v);
    }
    *(short8v*)(Wfrag + (size_t)tid * 8) = out;
}

// ---------------- gather: ns_bf[n] = bf16(mean_{s in nbr(n)} h_bf[s]) -----------------
__global__ __launch_bounds__(256) void gather_kernel(const int* __restrict__ start,
                                                     const int* __restrict__ cnt,
                                                     const int* __restrict__ srcs,
                                                     const float* __restrict__ inv,
                                                     const unsigned short* __restrict__ hb,
                                                     unsigned short* __restrict__ nsb) {
    const int idx  = blockIdx.x * 256 + threadIdx.x;
    const int node = idx >> 5;
    if (node >= N_NODES) return;
    const int f = (idx & 31) * 4;
    const int st = start[node];
    const int c  = cnt[node];
    float a0 = 0.f, a1 = 0.f, a2 = 0.f, a3 = 0.f;
    int j = 0;
    for (; j + 1 < c; j += 2) {
        const int s0 = srcs[st + j];
        const int s1 = srcs[st + j + 1];
        const ushort4 v0 = *(const ushort4*)(hb + (size_t)s0 * H + f);
        const ushort4 v1 = *(const ushort4*)(hb + (size_t)s1 * H + f);
        a0 += bf2f(v0.x); a1 += bf2f(v0.y); a2 += bf2f(v0.z); a3 += bf2f(v0.w);
        a0 += bf2f(v1.x); a1 += bf2f(v1.y); a2 += bf2f(v1.z); a3 += bf2f(v1.w);
    }
    if (j < c) {
        const int s0 = srcs[st + j];
        const ushort4 v0 = *(const ushort4*)(hb + (size_t)s0 * H + f);
        a0 += bf2f(v0.x); a1 += bf2f(v0.y); a2 += bf2f(v0.z); a3 += bf2f(v0.w);
    }
    const float iv = inv[node];
    ushort4 o;
    o.x = f2bf(a0 * iv); o.y = f2bf(a1 * iv); o.z = f2bf(a2 * iv); o.w = f2bf(a3 * iv);
    *(ushort4*)(nsb + (size_t)node * H + f) = o;
}

// ---------------- combine: out = relu([h|ns] @ [Ws;Wn] + b), K=256 MFMA ---------------
// 8 waves/block; wave-task = (tr, wc): 16 rows x 64 cols. B panel (32 frags) in VGPRs.
__global__ __launch_bounds__(512, 2) void combine_mfma(const short* __restrict__ Wfrag,
                                                       const float* __restrict__ bias,
                                                       const unsigned short* __restrict__ hb,
                                                       const unsigned short* __restrict__ nsb,
                                                       unsigned short* __restrict__ outb,
                                                       float* __restrict__ outf,
                                                       int last) {
    const int wave = threadIdx.x >> 6;
    const int lane = threadIdx.x & 63;
    const int wc   = wave & 1;          // task parity is constant per wave (stride even)

    short8v Bf[4][8];
    #pragma unroll
    for (int ct = 0; ct < 4; ++ct)
        #pragma unroll
        for (int ks = 0; ks < 8; ++ks)
            Bf[ct][ks] = ((const short8v*)Wfrag)[(size_t)(((wc * 4 + ct) * 8 + ks) * 64 + lane)];

    float bs[4];
    #pragma unroll
    for (int ct = 0; ct < 4; ++ct) bs[ct] = bias[wc * 64 + ct * 16 + (lane & 15)];

    const int ntasks = (N_NODES / 16) * 2;   // 62500
    for (int task = blockIdx.x * 8 + wave; task < ntasks; task += gridDim.x * 8) {
        const int r0 = (task >> 1) * 16;
        const unsigned short* arow = hb  + (size_t)(r0 + (lane & 15)) * H + (lane >> 4) * 8;
        const unsigned short* nrow = nsb + (size_t)(r0 + (lane & 15)) * H + (lane >> 4) * 8;
        short8v Af[8];
        #pragma unroll
        for (int ks = 0; ks < 4; ++ks) Af[ks]     = *(const short8v*)(arow + ks * 32);
        #pragma unroll
        for (int ks = 0; ks < 4; ++ks) Af[4 + ks] = *(const short8v*)(nrow + ks * 32);

        f32x4 acc[4];
        #pragma unroll
        for (int ct = 0; ct < 4; ++ct) acc[ct] = (f32x4){0.f, 0.f, 0.f, 0.f};
        #pragma unroll
        for (int ks = 0; ks < 8; ++ks)
            #pragma unroll
            for (int ct = 0; ct < 4; ++ct)
                acc[ct] = __builtin_amdgcn_mfma_f32_16x16x32_bf16(Af[ks], Bf[ct][ks], acc[ct], 0, 0, 0);

        if (!last) {
            #pragma unroll
            for (int ct = 0; ct < 4; ++ct) {
                const int col = wc * 64 + ct * 16 + (lane & 15);
                #pragma unroll
                for (int q = 0; q < 4; ++q) {
                    float v = fmaxf(acc[ct][q] + bs[ct], 0.f);
                    outb[(size_t)(r0 + (lane >> 4) * 4 + q) * H + col] = f2bf(v);
                }
            }
        } else {
            #pragma unroll
            for (int ct = 0; ct < 4; ++ct) {
                const int col = wc * 64 + ct * 16 + (lane & 15);
                #pragma unroll
                for (int q = 0; q < 4; ++q) {
                    float v = fmaxf(acc[ct][q] + bs[ct], 0.f);
                    outf[(size_t)(r0 + (lane >> 4) * 4 + q) * H + col] = v;
                }
            }
        }
    }
}

// ---------------- launch ----------------
extern "C" void kernel_launch(void* const* d_in, const int* in_sizes, int n_in,
                              void* d_out, int out_size, void* d_ws, size_t ws_size,
                              hipStream_t stream) {
    const float* x        = (const float*)d_in[0];
    const int*   edge_src = (const int*)d_in[1];
    const int*   edge_dst = (const int*)d_in[2];
    const float* W_in     = (const float*)d_in[3];
    const float* b_in     = (const float*)d_in[4];
    const float* W_self   = (const float*)d_in[5];
    const float* W_neigh  = (const float*)d_in[6];
    const float* b_layers = (const float*)d_in[7];

    // ws layout (272.2 MB total, all 16B-aligned)
    unsigned short* h0  = (unsigned short*)d_ws;               // 128 MB
    unsigned short* nsb = h0 + (size_t)N_NODES * H;            // 128 MB
    int*   cnt    = (int*)(nsb + (size_t)N_NODES * H);         // 2 MB
    int*   start  = cnt + N_NODES;                             // 2 MB
    int*   cursor = start + N_NODES;                           // 2 MB
    float* inv    = (float*)(cursor + N_NODES);                // 2 MB
    int*   srcs   = (int*)(inv + N_NODES);                     // 8 MB
    int*   bsums  = srcs + N_EDGES;                            // 1 KB
    short* Wfrag  = (short*)(bsums + 256);                     // 192 KB
    // h1 lives in d_out's storage (bf16, 128 MB of its 256 MB)
    unsigned short* h1 = (unsigned short*)d_out;

    proj_kernel<<<512, 256, 0, stream>>>(x, W_in, b_in, h0);

    zero_int_kernel<<<(N_NODES + 255) / 256, 256, 0, stream>>>(cnt, N_NODES);
    hist_kernel<<<(N_EDGES + 255) / 256, 256, 0, stream>>>(edge_dst, cnt);
    scan_reduce_kernel<<<NB_SCAN, 256, 0, stream>>>(cnt, bsums);
    scan_bsums_kernel<<<1, 256, 0, stream>>>(bsums);
    scan_final_kernel<<<NB_SCAN, 256, 0, stream>>>(cnt, bsums, start, cursor, inv);
    fill_kernel<<<(N_EDGES + 255) / 256, 256, 0, stream>>>(edge_src, edge_dst, cursor, srcs);
    prep_w_kernel<<<(NLAYERS * 64 * 64 + 255) / 256, 256, 0, stream>>>(W_self, W_neigh, Wfrag);

    const int gather_grid = (N_NODES * 32 + 255) / 256;
    // L0: read h0 -> write h1 ; L1: read h1 -> write h0 ; L2: read h0 -> write fp32 d_out
    gather_kernel<<<gather_grid, 256, 0, stream>>>(start, cnt, srcs, inv, h0, nsb);
    combine_mfma<<<1024, 512, 0, stream>>>(Wfrag + 0 * 64 * 64 * 8, b_layers + 0 * H,
                                           h0, nsb, h1, nullptr, 0);
    gather_kernel<<<gather_grid, 256, 0, stream>>>(start, cnt, srcs, inv, h1, nsb);
    combine_mfma<<<1024, 512, 0, stream>>>(Wfrag + 1 * 64 * 64 * 8, b_layers + 1 * H,
                                           h1, nsb, h0, nullptr, 0);
    gather_kernel<<<gather_grid, 256, 0, stream>>>(start, cnt, srcs, inv, h0, nsb);
    combine_mfma<<<1024, 512, 0, stream>>>(Wfrag + 2 * 64 * 64 * 8, b_layers + 2 * H,
                                           h0, nsb, nullptr, (float*)d_out, 1);
}

// Round 4
// 1120.891 us; speedup vs baseline: 12.8631x; 1.5674x over previous
//
#include <hip/hip_runtime.h>

#define N_NODES 500000
#define N_EDGES 2000000
#define F_IN 117
#define H 128
#define NLAYERS 3

#define SCAN_E 2048
#define NB_SCAN ((N_NODES + SCAN_E - 1) / SCAN_E)   // 245

typedef __attribute__((ext_vector_type(8))) short short8v;   // 8 bf16 (4 VGPR)
typedef __attribute__((ext_vector_type(4))) float f32x4;

__device__ __forceinline__ unsigned short f2bf(float x) {    // RNE fp32->bf16
    unsigned u = __builtin_bit_cast(unsigned, x);
    u += 0x7FFFu + ((u >> 16) & 1u);
    return (unsigned short)(u >> 16);
}
__device__ __forceinline__ float bf2f(unsigned short s) {
    unsigned u = ((unsigned)s) << 16;
    return __builtin_bit_cast(float, u);
}

// ---------------- x -> bf16, K-padded 117->128 (LDS-staged, coalesced) ----------------
__global__ __launch_bounds__(256) void convert_x_kernel(const float* __restrict__ x,
                                                        unsigned short* __restrict__ xb) {
    __shared__ float xs[8 * F_IN];   // 936 floats
    const int t = threadIdx.x;
    const int ngroups = N_NODES / 8;     // 62500
    for (int g = blockIdx.x; g < ngroups; g += gridDim.x) {
        const int r0 = g * 8;
        __syncthreads();                 // previous iter done reading xs
        const float* gx = x + (size_t)r0 * F_IN;
        for (int i = t; i < 8 * F_IN; i += 256) xs[i] = gx[i];
        __syncthreads();
        const int rr = t >> 5;           // 0..7
        const int c0 = (t & 31) * 4;     // 0..124
        ushort4 o;
        o.x = (c0 + 0 < F_IN) ? f2bf(xs[rr * F_IN + c0 + 0]) : 0;
        o.y = (c0 + 1 < F_IN) ? f2bf(xs[rr * F_IN + c0 + 1]) : 0;
        o.z = (c0 + 2 < F_IN) ? f2bf(xs[rr * F_IN + c0 + 2]) : 0;
        o.w = (c0 + 3 < F_IN) ? f2bf(xs[rr * F_IN + c0 + 3]) : 0;
        *(ushort4*)(xb + (size_t)(r0 + rr) * H + c0) = o;
    }
}

// ---------------- W prep: fp32 W[K][128] -> bf16 MFMA B-fragment order ----------------
// Generic over K-tiles: frag fi = (wc*4+ct)*nks+ks ; lane gets B[k=ks*32+(lane>>4)*8+j][c],
// c = wc*64+ct*16+(lane&15); k >= Kvalid reads as 0.
__global__ void prep_w_kernel(const float* __restrict__ Wself,
                              const float* __restrict__ Wneigh,
                              const float* __restrict__ Win,
                              short* __restrict__ Wfrag,     // [3][64][64][8]
                              short* __restrict__ WfragIn) { // [32][64][8]
    const int tid = blockIdx.x * 256 + threadIdx.x;
    const int total_cmb = NLAYERS * 64 * 64;                 // 12288 frags*lanes
    if (tid < total_cmb) {
        const int lane = tid & 63;
        const int fi   = (tid >> 6) & 63;
        const int l    = tid >> 12;
        const int ks = fi & 7, ct = (fi >> 3) & 3, wc = fi >> 5;
        const int c = wc * 64 + ct * 16 + (lane & 15);
        const int kbase = ks * 32 + (lane >> 4) * 8;
        short8v out;
        #pragma unroll
        for (int j = 0; j < 8; ++j) {
            int k = kbase + j;
            float v = (k < 128) ? Wself [(size_t)l * H * H + k * H + c]
                                : Wneigh[(size_t)l * H * H + (k - 128) * H + c];
            out[j] = (short)f2bf(v);
        }
        *(short8v*)(Wfrag + (size_t)tid * 8) = out;
    } else if (tid < total_cmb + 32 * 64) {
        const int t2 = tid - total_cmb;
        const int lane = t2 & 63;
        const int fi   = t2 >> 6;        // 0..31
        const int ks = fi & 3, ct = (fi >> 2) & 3, wc = fi >> 4;
        const int c = wc * 64 + ct * 16 + (lane & 15);
        const int kbase = ks * 32 + (lane >> 4) * 8;
        short8v out;
        #pragma unroll
        for (int j = 0; j < 8; ++j) {
            int k = kbase + j;
            out[j] = (k < F_IN) ? (short)f2bf(Win[(size_t)k * H + c]) : (short)0;
        }
        *(short8v*)(WfragIn + (size_t)t2 * 8) = out;
    }
}

// ---------------- proj: h = bf16(tanh(x_bf @ W_in + b_in)), K=128 MFMA ----------------
__global__ __launch_bounds__(512, 2) void proj_mfma(const short* __restrict__ WfragIn,
                                                    const float* __restrict__ bias,
                                                    const unsigned short* __restrict__ xb,
                                                    unsigned short* __restrict__ hb) {
    const int wave = threadIdx.x >> 6;
    const int lane = threadIdx.x & 63;
    const int wc   = wave & 1;

    short8v Bf[4][4];
    #pragma unroll
    for (int ct = 0; ct < 4; ++ct)
        #pragma unroll
        for (int ks = 0; ks < 4; ++ks)
            Bf[ct][ks] = ((const short8v*)WfragIn)[(size_t)(((wc * 4 + ct) * 4 + ks) * 64 + lane)];

    float bs[4];
    #pragma unroll
    for (int ct = 0; ct < 4; ++ct) bs[ct] = bias[wc * 64 + ct * 16 + (lane & 15)];

    const int ntasks = (N_NODES / 16) * 2;   // 62500
    for (int task = blockIdx.x * 8 + wave; task < ntasks; task += gridDim.x * 8) {
        const int r0 = (task >> 1) * 16;
        const unsigned short* arow = xb + (size_t)(r0 + (lane & 15)) * H + (lane >> 4) * 8;
        short8v Af[4];
        #pragma unroll
        for (int ks = 0; ks < 4; ++ks) Af[ks] = *(const short8v*)(arow + ks * 32);

        f32x4 acc[4];
        #pragma unroll
        for (int ct = 0; ct < 4; ++ct) acc[ct] = (f32x4){0.f, 0.f, 0.f, 0.f};
        #pragma unroll
        for (int ks = 0; ks < 4; ++ks)
            #pragma unroll
            for (int ct = 0; ct < 4; ++ct)
                acc[ct] = __builtin_amdgcn_mfma_f32_16x16x32_bf16(Af[ks], Bf[ct][ks], acc[ct], 0, 0, 0);

        #pragma unroll
        for (int ct = 0; ct < 4; ++ct) {
            const int col = wc * 64 + ct * 16 + (lane & 15);
            #pragma unroll
            for (int q = 0; q < 4; ++q) {
                float v = tanhf(acc[ct][q] + bs[ct]);
                hb[(size_t)(r0 + (lane >> 4) * 4 + q) * H + col] = f2bf(v);
            }
        }
    }
}

// ---------------- CSR build ----------------
__global__ void zero_int_kernel(int* __restrict__ p, int n) {
    int i = blockIdx.x * blockDim.x + threadIdx.x;
    if (i < n) p[i] = 0;
}

__global__ void hist_kernel(const int* __restrict__ dst, int* __restrict__ cnt) {
    int e = blockIdx.x * blockDim.x + threadIdx.x;
    if (e < N_EDGES) atomicAdd(&cnt[dst[e]], 1);
}

__global__ __launch_bounds__(256) void scan_reduce_kernel(const int* __restrict__ cnt,
                                                          int* __restrict__ bsums) {
    __shared__ int s[256];
    const int base = blockIdx.x * SCAN_E;
    int sum = 0;
    for (int i = threadIdx.x; i < SCAN_E; i += 256) {
        int idx = base + i;
        sum += (idx < N_NODES) ? cnt[idx] : 0;
    }
    s[threadIdx.x] = sum;
    __syncthreads();
    for (int off = 128; off > 0; off >>= 1) {
        if (threadIdx.x < off) s[threadIdx.x] += s[threadIdx.x + off];
        __syncthreads();
    }
    if (threadIdx.x == 0) bsums[blockIdx.x] = s[0];
}

__global__ void scan_bsums_kernel(int* __restrict__ bsums) {   // 1 block, 256 threads
    __shared__ int s[256];
    const int tid = threadIdx.x;
    int v = (tid < NB_SCAN) ? bsums[tid] : 0;
    s[tid] = v;
    __syncthreads();
    for (int off = 1; off < 256; off <<= 1) {
        int add = (tid >= off) ? s[tid - off] : 0;
        __syncthreads();
        s[tid] += add;
        __syncthreads();
    }
    if (tid < NB_SCAN) bsums[tid] = s[tid] - v;   // exclusive
}

__global__ __launch_bounds__(256) void scan_final_kernel(const int* __restrict__ cnt,
                                                         const int* __restrict__ bsums,
                                                         int* __restrict__ start,
                                                         int* __restrict__ cursor,
                                                         float* __restrict__ inv) {
    __shared__ int tsum[256];
    const int tid = threadIdx.x;
    const int base = blockIdx.x * SCAN_E + tid * 8;
    int c[8];
    int s = 0;
    #pragma unroll
    for (int k = 0; k < 8; ++k) {
        int idx = base + k;
        c[k] = (idx < N_NODES) ? cnt[idx] : 0;
        s += c[k];
    }
    tsum[tid] = s;
    __syncthreads();
    for (int off = 1; off < 256; off <<= 1) {
        int add = (tid >= off) ? tsum[tid - off] : 0;
        __syncthreads();
        tsum[tid] += add;
        __syncthreads();
    }
    int off0 = bsums[blockIdx.x] + tsum[tid] - s;
    #pragma unroll
    for (int k = 0; k < 8; ++k) {
        int idx = base + k;
        if (idx < N_NODES) {
            start[idx]  = off0;
            cursor[idx] = off0;
            inv[idx]    = 1.0f / fmaxf((float)c[k], 1.0f);
            off0 += c[k];
        }
    }
}

__global__ void fill_kernel(const int* __restrict__ src, const int* __restrict__ dst,
                            int* __restrict__ cursor, int* __restrict__ srcs) {
    int e = blockIdx.x * blockDim.x + threadIdx.x;
    if (e < N_EDGES) {
        int pos = atomicAdd(&cursor[dst[e]], 1);
        srcs[pos] = src[e];
    }
}

// ---------------- gather: ns_bf[n] = bf16(mean nbr h_bf), 16 lanes/node, 16B loads ----
__global__ __launch_bounds__(256) void gather_kernel(const int* __restrict__ start,
                                                     const int* __restrict__ cnt,
                                                     const int* __restrict__ srcs,
                                                     const float* __restrict__ inv,
                                                     const unsigned short* __restrict__ hb,
                                                     unsigned short* __restrict__ nsb) {
    const int idx  = blockIdx.x * 256 + threadIdx.x;
    const int node = idx >> 4;
    if (node >= N_NODES) return;
    const int f = (idx & 15) * 8;
    const int st = start[node];
    const int c  = cnt[node];
    float a[8];
    #pragma unroll
    for (int i = 0; i < 8; ++i) a[i] = 0.f;
    int j = 0;
    for (; j + 1 < c; j += 2) {
        const int s0 = srcs[st + j];
        const int s1 = srcs[st + j + 1];
        const short8v v0 = *(const short8v*)(hb + (size_t)s0 * H + f);
        const short8v v1 = *(const short8v*)(hb + (size_t)s1 * H + f);
        #pragma unroll
        for (int i = 0; i < 8; ++i) a[i] += bf2f((unsigned short)v0[i]);
        #pragma unroll
        for (int i = 0; i < 8; ++i) a[i] += bf2f((unsigned short)v1[i]);
    }
    if (j < c) {
        const int s0 = srcs[st + j];
        const short8v v0 = *(const short8v*)(hb + (size_t)s0 * H + f);
        #pragma unroll
        for (int i = 0; i < 8; ++i) a[i] += bf2f((unsigned short)v0[i]);
    }
    const float iv = inv[node];
    short8v o;
    #pragma unroll
    for (int i = 0; i < 8; ++i) o[i] = (short)f2bf(a[i] * iv);
    *(short8v*)(nsb + (size_t)node * H + f) = o;
}

// ---------------- combine: out = relu([h|ns] @ [Ws;Wn] + b), K=256 MFMA ---------------
__global__ __launch_bounds__(512, 2) void combine_mfma(const short* __restrict__ Wfrag,
                                                       const float* __restrict__ bias,
                                                       const unsigned short* __restrict__ hb,
                                                       const unsigned short* __restrict__ nsb,
                                                       unsigned short* __restrict__ outb,
                                                       float* __restrict__ outf,
                                                       int last) {
    const int wave = threadIdx.x >> 6;
    const int lane = threadIdx.x & 63;
    const int wc   = wave & 1;

    short8v Bf[4][8];
    #pragma unroll
    for (int ct = 0; ct < 4; ++ct)
        #pragma unroll
        for (int ks = 0; ks < 8; ++ks)
            Bf[ct][ks] = ((const short8v*)Wfrag)[(size_t)(((wc * 4 + ct) * 8 + ks) * 64 + lane)];

    float bs[4];
    #pragma unroll
    for (int ct = 0; ct < 4; ++ct) bs[ct] = bias[wc * 64 + ct * 16 + (lane & 15)];

    const int ntasks = (N_NODES / 16) * 2;   // 62500
    for (int task = blockIdx.x * 8 + wave; task < ntasks; task += gridDim.x * 8) {
        const int r0 = (task >> 1) * 16;
        const unsigned short* arow = hb  + (size_t)(r0 + (lane & 15)) * H + (lane >> 4) * 8;
        const unsigned short* nrow = nsb + (size_t)(r0 + (lane & 15)) * H + (lane >> 4) * 8;
        short8v Af[8];
        #pragma unroll
        for (int ks = 0; ks < 4; ++ks) Af[ks]     = *(const short8v*)(arow + ks * 32);
        #pragma unroll
        for (int ks = 0; ks < 4; ++ks) Af[4 + ks] = *(const short8v*)(nrow + ks * 32);

        f32x4 acc[4];
        #pragma unroll
        for (int ct = 0; ct < 4; ++ct) acc[ct] = (f32x4){0.f, 0.f, 0.f, 0.f};
        #pragma unroll
        for (int ks = 0; ks < 8; ++ks)
            #pragma unroll
            for (int ct = 0; ct < 4; ++ct)
                acc[ct] = __builtin_amdgcn_mfma_f32_16x16x32_bf16(Af[ks], Bf[ct][ks], acc[ct], 0, 0, 0);

        if (!last) {
            #pragma unroll
            for (int ct = 0; ct < 4; ++ct) {
                const int col = wc * 64 + ct * 16 + (lane & 15);
                #pragma unroll
                for (int q = 0; q < 4; ++q) {
                    float v = fmaxf(acc[ct][q] + bs[ct], 0.f);
                    outb[(size_t)(r0 + (lane >> 4) * 4 + q) * H + col] = f2bf(v);
                }
            }
        } else {
            #pragma unroll
            for (int ct = 0; ct < 4; ++ct) {
                const int col = wc * 64 + ct * 16 + (lane & 15);
                #pragma unroll
                for (int q = 0; q < 4; ++q) {
                    float v = fmaxf(acc[ct][q] + bs[ct], 0.f);
                    outf[(size_t)(r0 + (lane >> 4) * 4 + q) * H + col] = v;
                }
            }
        }
    }
}

// ---------------- launch ----------------
extern "C" void kernel_launch(void* const* d_in, const int* in_sizes, int n_in,
                              void* d_out, int out_size, void* d_ws, size_t ws_size,
                              hipStream_t stream) {
    const float* x        = (const float*)d_in[0];
    const int*   edge_src = (const int*)d_in[1];
    const int*   edge_dst = (const int*)d_in[2];
    const float* W_in     = (const float*)d_in[3];
    const float* b_in     = (const float*)d_in[4];
    const float* W_self   = (const float*)d_in[5];
    const float* W_neigh  = (const float*)d_in[6];
    const float* b_layers = (const float*)d_in[7];

    // ws layout (~272.4 MB, all 16B-aligned)
    unsigned short* h0  = (unsigned short*)d_ws;               // 128 MB
    unsigned short* nsb = h0 + (size_t)N_NODES * H;            // 128 MB
    int*   cnt    = (int*)(nsb + (size_t)N_NODES * H);         // 2 MB
    int*   start  = cnt + N_NODES;                             // 2 MB
    int*   cursor = start + N_NODES;                           // 2 MB
    float* inv    = (float*)(cursor + N_NODES);                // 2 MB
    int*   srcs   = (int*)(inv + N_NODES);                     // 8 MB
    int*   bsums  = srcs + N_EDGES;                            // 1 KB
    short* Wfrag  = (short*)(bsums + 256);                     // 192 KB  [3][64][64][8]
    short* WfragIn = Wfrag + (size_t)NLAYERS * 64 * 64 * 8;    // 32 KB   [32][64][8]
    // d_out (256 MB fp32) double-duty: lower 128 MB = h1 (bf16), upper 128 MB = x_bf
    unsigned short* h1 = (unsigned short*)d_out;
    unsigned short* xb = h1 + (size_t)N_NODES * H;

    // x -> bf16 (padded) and weight fragment prep
    convert_x_kernel<<<8192, 256, 0, stream>>>(x, xb);
    prep_w_kernel<<<(NLAYERS * 64 * 64 + 32 * 64 + 255) / 256, 256, 0, stream>>>(
        W_self, W_neigh, W_in, Wfrag, WfragIn);

    // CSR build (edge_dst static)
    zero_int_kernel<<<(N_NODES + 255) / 256, 256, 0, stream>>>(cnt, N_NODES);
    hist_kernel<<<(N_EDGES + 255) / 256, 256, 0, stream>>>(edge_dst, cnt);
    scan_reduce_kernel<<<NB_SCAN, 256, 0, stream>>>(cnt, bsums);
    scan_bsums_kernel<<<1, 256, 0, stream>>>(bsums);
    scan_final_kernel<<<NB_SCAN, 256, 0, stream>>>(cnt, bsums, start, cursor, inv);
    fill_kernel<<<(N_EDGES + 255) / 256, 256, 0, stream>>>(edge_src, edge_dst, cursor, srcs);

    // input projection (MFMA, K=128, tanh epilogue)
    proj_mfma<<<1024, 512, 0, stream>>>(WfragIn, b_in, xb, h0);

    const int gather_grid = (N_NODES * 16 + 255) / 256;
    // L0: h0 -> h1 ; L1: h1 -> h0 ; L2: h0 -> fp32 d_out
    gather_kernel<<<gather_grid, 256, 0, stream>>>(start, cnt, srcs, inv, h0, nsb);
    combine_mfma<<<1024, 512, 0, stream>>>(Wfrag + 0 * 64 * 64 * 8, b_layers + 0 * H,
                                           h0, nsb, h1, nullptr, 0);
    gather_kernel<<<gather_grid, 256, 0, stream>>>(start, cnt, srcs, inv, h1, nsb);
    combine_mfma<<<1024, 512, 0, stream>>>(Wfrag + 1 * 64 * 64 * 8, b_layers + 1 * H,
                                           h1, nsb, h0, nullptr, 0);
    gather_kernel<<<gather_grid, 256, 0, stream>>>(start, cnt, srcs, inv, h0, nsb);
    combine_mfma<<<1024, 512, 0, stream>>>(Wfrag + 2 * 64 * 64 * 8, b_layers + 2 * H,
                                           h0, nsb, nullptr, (float*)d_out, 1);
}

// Round 5
// 1030.791 us; speedup vs baseline: 13.9874x; 1.0874x over previous
//
#include <hip/hip_runtime.h>

#define N_NODES 500000
#define N_EDGES 2000000
#define F_IN 117
#define H 128
#define NLAYERS 3

#define SCAN_E 2048
#define NB_SCAN ((N_NODES + SCAN_E - 1) / SCAN_E)   // 245

typedef __attribute__((ext_vector_type(8))) short short8v;   // 8 bf16 (4 VGPR)
typedef __attribute__((ext_vector_type(4))) float f32x4;

__device__ __forceinline__ unsigned short f2bf(float x) {    // RNE fp32->bf16
    unsigned u = __builtin_bit_cast(unsigned, x);
    u += 0x7FFFu + ((u >> 16) & 1u);
    return (unsigned short)(u >> 16);
}
__device__ __forceinline__ float bf2f(unsigned short s) {
    unsigned u = ((unsigned)s) << 16;
    return __builtin_bit_cast(float, u);
}
// tanh(x) = 1 - 2/(exp(2x)+1): 1 exp2 + 1 rcp, NaN-free at both extremes.
__device__ __forceinline__ float fast_tanh(float x) {
    float e = __builtin_amdgcn_exp2f(x * 2.885390081777927f);   // exp(2x)
    return 1.0f - 2.0f * __builtin_amdgcn_rcpf(e + 1.0f);
}

// ---------------- W prep: fp32 W[K][128] -> bf16 MFMA B-fragment order ----------------
__global__ void prep_w_kernel(const float* __restrict__ Wself,
                              const float* __restrict__ Wneigh,
                              const float* __restrict__ Win,
                              short* __restrict__ Wfrag,     // [3][64][64][8]
                              short* __restrict__ WfragIn) { // [32][64][8]
    const int tid = blockIdx.x * 256 + threadIdx.x;
    const int total_cmb = NLAYERS * 64 * 64;                 // 12288 frags*lanes
    if (tid < total_cmb) {
        const int lane = tid & 63;
        const int fi   = (tid >> 6) & 63;
        const int l    = tid >> 12;
        const int ks = fi & 7, ct = (fi >> 3) & 3, wc = fi >> 5;
        const int c = wc * 64 + ct * 16 + (lane & 15);
        const int kbase = ks * 32 + (lane >> 4) * 8;
        short8v out;
        #pragma unroll
        for (int j = 0; j < 8; ++j) {
            int k = kbase + j;
            float v = (k < 128) ? Wself [(size_t)l * H * H + k * H + c]
                                : Wneigh[(size_t)l * H * H + (k - 128) * H + c];
            out[j] = (short)f2bf(v);
        }
        *(short8v*)(Wfrag + (size_t)tid * 8) = out;
    } else if (tid < total_cmb + 32 * 64) {
        const int t2 = tid - total_cmb;
        const int lane = t2 & 63;
        const int fi   = t2 >> 6;        // 0..31
        const int ks = fi & 3, ct = (fi >> 2) & 3, wc = fi >> 4;
        const int c = wc * 64 + ct * 16 + (lane & 15);
        const int kbase = ks * 32 + (lane >> 4) * 8;
        short8v out;
        #pragma unroll
        for (int j = 0; j < 8; ++j) {
            int k = kbase + j;
            out[j] = (k < F_IN) ? (short)f2bf(Win[(size_t)k * H + c]) : (short)0;
        }
        *(short8v*)(WfragIn + (size_t)t2 * 8) = out;
    }
}

// ---------------- proj: h = bf16(tanh(x @ W_in + b_in)), fp32 x read direct -----------
// A-fragments converted in-kernel; cols >= 117 hit zeroed B rows (product = 0).
// Only node 499999's lane can spill past the allocation -> masked branch there.
__global__ __launch_bounds__(512, 2) void proj_mfma(const short* __restrict__ WfragIn,
                                                    const float* __restrict__ bias,
                                                    const float* __restrict__ x,
                                                    unsigned short* __restrict__ hb) {
    const int wave = threadIdx.x >> 6;
    const int lane = threadIdx.x & 63;
    const int wc   = wave & 1;

    short8v Bf[4][4];
    #pragma unroll
    for (int ct = 0; ct < 4; ++ct)
        #pragma unroll
        for (int ks = 0; ks < 4; ++ks)
            Bf[ct][ks] = ((const short8v*)WfragIn)[(size_t)(((wc * 4 + ct) * 4 + ks) * 64 + lane)];

    float bs[4];
    #pragma unroll
    for (int ct = 0; ct < 4; ++ct) bs[ct] = bias[wc * 64 + ct * 16 + (lane & 15)];

    const int cbase = (lane >> 4) * 8;
    const int ntasks = (N_NODES / 16) * 2;   // 62500
    for (int task = blockIdx.x * 8 + wave; task < ntasks; task += gridDim.x * 8) {
        const int r0  = (task >> 1) * 16;
        const int row = r0 + (lane & 15);
        const float* xr = x + (size_t)row * F_IN;

        short8v Af[4];
        #pragma unroll
        for (int ks = 0; ks < 4; ++ks) {
            const int k0 = ks * 32 + cbase;
            short8v a;
            if (row == N_NODES - 1 && k0 + 7 >= F_IN) {   // rare: avoid OOB past x[]
                #pragma unroll
                for (int j = 0; j < 8; ++j) {
                    int k = k0 + j;
                    a[j] = (k < F_IN) ? (short)f2bf(xr[k]) : (short)0;
                }
            } else {
                #pragma unroll
                for (int j = 0; j < 8; ++j) a[j] = (short)f2bf(xr[k0 + j]);
            }
            Af[ks] = a;
        }

        f32x4 acc[4];
        #pragma unroll
        for (int ct = 0; ct < 4; ++ct) acc[ct] = (f32x4){0.f, 0.f, 0.f, 0.f};
        #pragma unroll
        for (int ks = 0; ks < 4; ++ks)
            #pragma unroll
            for (int ct = 0; ct < 4; ++ct)
                acc[ct] = __builtin_amdgcn_mfma_f32_16x16x32_bf16(Af[ks], Bf[ct][ks], acc[ct], 0, 0, 0);

        #pragma unroll
        for (int ct = 0; ct < 4; ++ct) {
            const int col = wc * 64 + ct * 16 + (lane & 15);
            #pragma unroll
            for (int q = 0; q < 4; ++q) {
                float v = fast_tanh(acc[ct][q] + bs[ct]);
                hb[(size_t)(r0 + (lane >> 4) * 4 + q) * H + col] = f2bf(v);
            }
        }
    }
}

// ---------------- CSR build ----------------
__global__ void zero_int_kernel(int* __restrict__ p, int n) {
    int i = blockIdx.x * blockDim.x + threadIdx.x;
    if (i < n) p[i] = 0;
}

__global__ void hist_kernel(const int* __restrict__ dst, int* __restrict__ cnt) {
    int e = blockIdx.x * blockDim.x + threadIdx.x;
    if (e < N_EDGES) atomicAdd(&cnt[dst[e]], 1);
}

__global__ __launch_bounds__(256) void scan_reduce_kernel(const int* __restrict__ cnt,
                                                          int* __restrict__ bsums) {
    __shared__ int s[256];
    const int base = blockIdx.x * SCAN_E;
    int sum = 0;
    for (int i = threadIdx.x; i < SCAN_E; i += 256) {
        int idx = base + i;
        sum += (idx < N_NODES) ? cnt[idx] : 0;
    }
    s[threadIdx.x] = sum;
    __syncthreads();
    for (int off = 128; off > 0; off >>= 1) {
        if (threadIdx.x < off) s[threadIdx.x] += s[threadIdx.x + off];
        __syncthreads();
    }
    if (threadIdx.x == 0) bsums[blockIdx.x] = s[0];
}

__global__ void scan_bsums_kernel(int* __restrict__ bsums) {   // 1 block, 256 threads
    __shared__ int s[256];
    const int tid = threadIdx.x;
    int v = (tid < NB_SCAN) ? bsums[tid] : 0;
    s[tid] = v;
    __syncthreads();
    for (int off = 1; off < 256; off <<= 1) {
        int add = (tid >= off) ? s[tid - off] : 0;
        __syncthreads();
        s[tid] += add;
        __syncthreads();
    }
    if (tid < NB_SCAN) bsums[tid] = s[tid] - v;   // exclusive
}

__global__ __launch_bounds__(256) void scan_final_kernel(const int* __restrict__ cnt,
                                                         const int* __restrict__ bsums,
                                                         int* __restrict__ start,
                                                         int* __restrict__ cursor,
                                                         float* __restrict__ inv) {
    __shared__ int tsum[256];
    const int tid = threadIdx.x;
    const int base = blockIdx.x * SCAN_E + tid * 8;
    int c[8];
    int s = 0;
    #pragma unroll
    for (int k = 0; k < 8; ++k) {
        int idx = base + k;
        c[k] = (idx < N_NODES) ? cnt[idx] : 0;
        s += c[k];
    }
    tsum[tid] = s;
    __syncthreads();
    for (int off = 1; off < 256; off <<= 1) {
        int add = (tid >= off) ? tsum[tid - off] : 0;
        __syncthreads();
        tsum[tid] += add;
        __syncthreads();
    }
    int off0 = bsums[blockIdx.x] + tsum[tid] - s;
    #pragma unroll
    for (int k = 0; k < 8; ++k) {
        int idx = base + k;
        if (idx < N_NODES) {
            start[idx]  = off0;
            cursor[idx] = off0;
            inv[idx]    = 1.0f / fmaxf((float)c[k], 1.0f);
            off0 += c[k];
        }
    }
}

__global__ void fill_kernel(const int* __restrict__ src, const int* __restrict__ dst,
                            int* __restrict__ cursor, int* __restrict__ srcs) {
    int e = blockIdx.x * blockDim.x + threadIdx.x;
    if (e < N_EDGES) {
        int pos = atomicAdd(&cursor[dst[e]], 1);
        srcs[pos] = src[e];
    }
}

// ---------------- gather: ns_bf[n] = bf16(mean nbr h_bf), 16 lanes/node, unroll-4 ----
__global__ __launch_bounds__(256) void gather_kernel(const int* __restrict__ start,
                                                     const int* __restrict__ cnt,
                                                     const int* __restrict__ srcs,
                                                     const float* __restrict__ inv,
                                                     const unsigned short* __restrict__ hb,
                                                     unsigned short* __restrict__ nsb) {
    const int idx  = blockIdx.x * 256 + threadIdx.x;
    const int node = idx >> 4;
    if (node >= N_NODES) return;
    const int f = (idx & 15) * 8;
    const int st = start[node];
    const int c  = cnt[node];
    float a[8];
    #pragma unroll
    for (int i = 0; i < 8; ++i) a[i] = 0.f;
    int j = 0;
    for (; j + 4 <= c; j += 4) {           // 4 outstanding 16B loads
        const int s0 = srcs[st + j + 0];
        const int s1 = srcs[st + j + 1];
        const int s2 = srcs[st + j + 2];
        const int s3 = srcs[st + j + 3];
        const short8v v0 = *(const short8v*)(hb + (size_t)s0 * H + f);
        const short8v v1 = *(const short8v*)(hb + (size_t)s1 * H + f);
        const short8v v2 = *(const short8v*)(hb + (size_t)s2 * H + f);
        const short8v v3 = *(const short8v*)(hb + (size_t)s3 * H + f);
        #pragma unroll
        for (int i = 0; i < 8; ++i)
            a[i] += (bf2f((unsigned short)v0[i]) + bf2f((unsigned short)v1[i]))
                  + (bf2f((unsigned short)v2[i]) + bf2f((unsigned short)v3[i]));
    }
    if (j + 2 <= c) {
        const int s0 = srcs[st + j + 0];
        const int s1 = srcs[st + j + 1];
        const short8v v0 = *(const short8v*)(hb + (size_t)s0 * H + f);
        const short8v v1 = *(const short8v*)(hb + (size_t)s1 * H + f);
        #pragma unroll
        for (int i = 0; i < 8; ++i)
            a[i] += bf2f((unsigned short)v0[i]) + bf2f((unsigned short)v1[i]);
        j += 2;
    }
    if (j < c) {
        const int s0 = srcs[st + j];
        const short8v v0 = *(const short8v*)(hb + (size_t)s0 * H + f);
        #pragma unroll
        for (int i = 0; i < 8; ++i) a[i] += bf2f((unsigned short)v0[i]);
    }
    const float iv = inv[node];
    short8v o;
    #pragma unroll
    for (int i = 0; i < 8; ++i) o[i] = (short)f2bf(a[i] * iv);
    *(short8v*)(nsb + (size_t)node * H + f) = o;
}

// ---------------- combine: out = relu([h|ns] @ [Ws;Wn] + b), K=256 MFMA ---------------
__global__ __launch_bounds__(512, 2) void combine_mfma(const short* __restrict__ Wfrag,
                                                       const float* __restrict__ bias,
                                                       const unsigned short* __restrict__ hb,
                                                       const unsigned short* __restrict__ nsb,
                                                       unsigned short* __restrict__ outb,
                                                       float* __restrict__ outf,
                                                       int last) {
    const int wave = threadIdx.x >> 6;
    const int lane = threadIdx.x & 63;
    const int wc   = wave & 1;

    short8v Bf[4][8];
    #pragma unroll
    for (int ct = 0; ct < 4; ++ct)
        #pragma unroll
        for (int ks = 0; ks < 8; ++ks)
            Bf[ct][ks] = ((const short8v*)Wfrag)[(size_t)(((wc * 4 + ct) * 8 + ks) * 64 + lane)];

    float bs[4];
    #pragma unroll
    for (int ct = 0; ct < 4; ++ct) bs[ct] = bias[wc * 64 + ct * 16 + (lane & 15)];

    const int ntasks = (N_NODES / 16) * 2;   // 62500
    for (int task = blockIdx.x * 8 + wave; task < ntasks; task += gridDim.x * 8) {
        const int r0 = (task >> 1) * 16;
        const unsigned short* arow = hb  + (size_t)(r0 + (lane & 15)) * H + (lane >> 4) * 8;
        const unsigned short* nrow = nsb + (size_t)(r0 + (lane & 15)) * H + (lane >> 4) * 8;
        short8v Af[8];
        #pragma unroll
        for (int ks = 0; ks < 4; ++ks) Af[ks]     = *(const short8v*)(arow + ks * 32);
        #pragma unroll
        for (int ks = 0; ks < 4; ++ks) Af[4 + ks] = *(const short8v*)(nrow + ks * 32);

        f32x4 acc[4];
        #pragma unroll
        for (int ct = 0; ct < 4; ++ct) acc[ct] = (f32x4){0.f, 0.f, 0.f, 0.f};
        #pragma unroll
        for (int ks = 0; ks < 8; ++ks)
            #pragma unroll
            for (int ct = 0; ct < 4; ++ct)
                acc[ct] = __builtin_amdgcn_mfma_f32_16x16x32_bf16(Af[ks], Bf[ct][ks], acc[ct], 0, 0, 0);

        if (!last) {
            #pragma unroll
            for (int ct = 0; ct < 4; ++ct) {
                const int col = wc * 64 + ct * 16 + (lane & 15);
                #pragma unroll
                for (int q = 0; q < 4; ++q) {
                    float v = fmaxf(acc[ct][q] + bs[ct], 0.f);
                    outb[(size_t)(r0 + (lane >> 4) * 4 + q) * H + col] = f2bf(v);
                }
            }
        } else {
            #pragma unroll
            for (int ct = 0; ct < 4; ++ct) {
                const int col = wc * 64 + ct * 16 + (lane & 15);
                #pragma unroll
                for (int q = 0; q < 4; ++q) {
                    float v = fmaxf(acc[ct][q] + bs[ct], 0.f);
                    outf[(size_t)(r0 + (lane >> 4) * 4 + q) * H + col] = v;
                }
            }
        }
    }
}

// ---------------- launch ----------------
extern "C" void kernel_launch(void* const* d_in, const int* in_sizes, int n_in,
                              void* d_out, int out_size, void* d_ws, size_t ws_size,
                              hipStream_t stream) {
    const float* x        = (const float*)d_in[0];
    const int*   edge_src = (const int*)d_in[1];
    const int*   edge_dst = (const int*)d_in[2];
    const float* W_in     = (const float*)d_in[3];
    const float* b_in     = (const float*)d_in[4];
    const float* W_self   = (const float*)d_in[5];
    const float* W_neigh  = (const float*)d_in[6];
    const float* b_layers = (const float*)d_in[7];

    // ws layout (~272.4 MB, all 16B-aligned)
    unsigned short* h0  = (unsigned short*)d_ws;               // 128 MB
    unsigned short* nsb = h0 + (size_t)N_NODES * H;            // 128 MB
    int*   cnt    = (int*)(nsb + (size_t)N_NODES * H);         // 2 MB
    int*   start  = cnt + N_NODES;                             // 2 MB
    int*   cursor = start + N_NODES;                           // 2 MB
    float* inv    = (float*)(cursor + N_NODES);                // 2 MB
    int*   srcs   = (int*)(inv + N_NODES);                     // 8 MB
    int*   bsums  = srcs + N_EDGES;                            // 1 KB
    short* Wfrag  = (short*)(bsums + 256);                     // 192 KB  [3][64][64][8]
    short* WfragIn = Wfrag + (size_t)NLAYERS * 64 * 64 * 8;    // 32 KB   [32][64][8]
    // h1 (bf16) lives in d_out's lower 128 MB until the final fp32 write
    unsigned short* h1 = (unsigned short*)d_out;

    prep_w_kernel<<<(NLAYERS * 64 * 64 + 32 * 64 + 255) / 256, 256, 0, stream>>>(
        W_self, W_neigh, W_in, Wfrag, WfragIn);

    // CSR build (edge_dst static)
    zero_int_kernel<<<(N_NODES + 255) / 256, 256, 0, stream>>>(cnt, N_NODES);
    hist_kernel<<<(N_EDGES + 255) / 256, 256, 0, stream>>>(edge_dst, cnt);
    scan_reduce_kernel<<<NB_SCAN, 256, 0, stream>>>(cnt, bsums);
    scan_bsums_kernel<<<1, 256, 0, stream>>>(bsums);
    scan_final_kernel<<<NB_SCAN, 256, 0, stream>>>(cnt, bsums, start, cursor, inv);
    fill_kernel<<<(N_EDGES + 255) / 256, 256, 0, stream>>>(edge_src, edge_dst, cursor, srcs);

    // input projection (MFMA, fused fp32->bf16 convert, fast-tanh epilogue)
    proj_mfma<<<1024, 512, 0, stream>>>(WfragIn, b_in, x, h0);

    const int gather_grid = (N_NODES * 16 + 255) / 256;
    // L0: h0 -> h1 ; L1: h1 -> h0 ; L2: h0 -> fp32 d_out
    gather_kernel<<<gather_grid, 256, 0, stream>>>(start, cnt, srcs, inv, h0, nsb);
    combine_mfma<<<1024, 512, 0, stream>>>(Wfrag + 0 * 64 * 64 * 8, b_layers + 0 * H,
                                           h0, nsb, h1, nullptr, 0);
    gather_kernel<<<gather_grid, 256, 0, stream>>>(start, cnt, srcs, inv, h1, nsb);
    combine_mfma<<<1024, 512, 0, stream>>>(Wfrag + 1 * 64 * 64 * 8, b_layers + 1 * H,
                                           h1, nsb, h0, nullptr, 0);
    gather_kernel<<<gather_grid, 256, 0, stream>>>(start, cnt, srcs, inv, h0, nsb);
    combine_mfma<<<1024, 512, 0, stream>>>(Wfrag + 2 * 64 * 64 * 8, b_layers + 2 * H,
                                           h0, nsb, nullptr, (float*)d_out, 1);
}